// Round 1
// baseline (295.773 us; speedup 1.0000x reference)
//
#include <hip/hip_runtime.h>
#include <hip/hip_bf16.h>
#include <math.h>

#define LEN 128
#define NCELLS 8256          // LEN*(LEN+1)/2
#define TOTAL 349504         // sum_{l=1}^{127} (128-l)*l
#define NCONSTR 8
#define BONUS 1000.0f
#define NT 512               // threads per block
#define MAXK 8               // max staged elements per thread: 4096/512

__device__ __forceinline__ int OFFi(int n) {
    // OFF[n] = 128n - n(n-1)/2 = n*(257-n)/2
    return (n * (257 - n)) >> 1;
}

__global__ __launch_bounds__(NT)
void cky_fused_kernel(const float* __restrict__ scores,
                      const int* __restrict__ cpos,
                      float* __restrict__ ws) {
    __shared__ float2 chart[NCELLS];   // .x = pred chart, .y = constr chart
    __shared__ float  sbuf[4160];      // max over levels of L*(N+1)

    const int b   = blockIdx.x;
    const int tid = threadIdx.x;
    const float* __restrict__ g = scores + (size_t)b * TOTAL;

    // ---- init both charts to zero ----
    for (int i = tid; i < NCELLS; i += NT) chart[i] = make_float2(0.f, 0.f);
    __syncthreads();
    // ---- set BONUS at constraint positions (set, not add; duplicates OK) ----
    if (tid < NCONSTR) {
        int p = cpos[b * NCONSTR + tid];
        chart[p].y = BONUS;
    }

    // ---- prefetch level 1 scores into registers ----
    float r[MAXK];
    int soff = 0;
    int cnt  = (LEN - 1) * 1;
    #pragma unroll
    for (int k = 0; k < MAXK; k++) {
        int idx = tid + k * NT;
        r[k] = (idx < cnt) ? g[soff + idx] : 0.f;
    }

    for (int level = 1; level < LEN; level++) {
        const int N = level;
        const int L = LEN - level;
        const int cnt_cur = cnt;

        // ---- write staged regs into padded LDS: sbuf[pos*(N+1)+n] ----
        #pragma unroll
        for (int k = 0; k < MAXK; k++) {
            unsigned idx = (unsigned)(tid + k * NT);
            if (idx < (unsigned)cnt_cur) {
                unsigned p_ = idx / (unsigned)N;
                unsigned n_ = idx - p_ * (unsigned)N;
                sbuf[p_ * (N + 1) + n_] = r[k];
            }
        }

        // ---- issue next level's global loads (overlap with this level's compute) ----
        const int soff_n = soff + cnt_cur;
        int cnt_n = 0;
        if (level + 1 < LEN) {
            cnt_n = (LEN - level - 1) * (level + 1);
            #pragma unroll
            for (int k = 0; k < MAXK; k++) {
                int idx = tid + k * NT;
                r[k] = (idx < cnt_n) ? g[soff_n + idx] : 0.f;
            }
        }

        __syncthreads();   // sbuf (and first-iter chart/constraints) visible

        // ---- compute: split-K over tpp lanes per cell ----
        int tpp = 1;
        {
            int v = NT / L;                 // >= 4 since L <= 127
            while ((tpp << 1) <= v && tpp < 64) tpp <<= 1;
        }
        const int pos = tid / tpp;
        const int sub = tid - pos * tpp;

        float bp = -INFINITY, bc = -INFINITY;
        if (pos < L) {
            const int base_s = pos * (N + 1);
            for (int n = sub; n < N; n += tpp) {
                const int l_idx = OFFi(n) + pos;
                const int m     = level - 1 - n;
                const int r_idx = OFFi(m) + pos + n + 1;
                const float2 l2 = chart[l_idx];
                const float2 r2 = chart[r_idx];
                const float  x  = sbuf[base_s + n];
                bp = fmaxf(bp, l2.x + r2.x + x);
                bc = fmaxf(bc, l2.y + r2.y + x);
            }
        }
        // reduce across the tpp lanes of this cell (tpp divides 64, groups aligned)
        for (int mm = tpp >> 1; mm > 0; mm >>= 1) {
            bp = fmaxf(bp, __shfl_xor(bp, mm));
            bc = fmaxf(bc, __shfl_xor(bc, mm));
        }
        if (pos < L && sub == 0) {
            const int q = OFFi(level) + pos;
            float2 c = chart[q];
            c.x += bp;
            c.y += bc;
            chart[q] = c;
        }

        __syncthreads();   // chart updated; sbuf free for overwrite

        soff = soff_n;
        cnt  = cnt_n;
    }

    // ---- per-batch hinge contribution ----
    if (tid == 0) {
        const float2 f = chart[NCELLS - 1];
        const float pred   = f.x;
        const float constr = f.y - BONUS * NCONSTR;
        const float diff   = pred - constr;
        const float mask   = (fabsf(diff) >= 0.001f) ? 1.f : 0.f;
        const float hinge  = fmaxf(1.0f + diff, 0.f) * mask;
        atomicAdd(ws + 0, hinge);
        atomicAdd(ws + 1, mask);
    }
}

__global__ void final_kernel(const float* __restrict__ ws, float* __restrict__ out) {
    const float h = ws[0];
    const float m = ws[1];
    out[0] = (m > 0.1f) ? (h / fmaxf(m, 1.f)) : h;
}

extern "C" void kernel_launch(void* const* d_in, const int* in_sizes, int n_in,
                              void* d_out, int out_size, void* d_ws, size_t ws_size,
                              hipStream_t stream) {
    const float* scores = (const float*)d_in[0];
    const int*   cpos   = (const int*)d_in[1];
    float* out = (float*)d_out;
    float* ws  = (float*)d_ws;

    hipMemsetAsync(ws, 0, 2 * sizeof(float), stream);
    cky_fused_kernel<<<dim3(256), dim3(NT), 0, stream>>>(scores, cpos, ws);
    final_kernel<<<dim3(1), dim3(1), 0, stream>>>(ws, out);
}

// Round 2
// 192.722 us; speedup vs baseline: 1.5347x; 1.5347x over previous
//
#include <hip/hip_runtime.h>
#include <hip/hip_bf16.h>
#include <math.h>

#define LEN 128
#define NCELLS 8256          // LEN*(LEN+1)/2
#define TOTAL 349504         // sum_{l=1}^{127} (128-l)*l
#define NCONSTR 8
#define BONUS 1000.0f
#define NT 512               // threads per block
#define MAXJ 16              // max score elements per thread per level

__device__ __forceinline__ int OFFi(int n) {
    // OFF[n] = n*(257-n)/2
    return (n * (257 - n)) >> 1;
}

// Barrier WITHOUT vmcnt drain: only LDS (chart) writes must be ordered.
// Register prefetch loads stay in flight across the barrier.
__device__ __forceinline__ void level_barrier() {
    __builtin_amdgcn_sched_barrier(0);
    asm volatile("s_waitcnt lgkmcnt(0)\n\ts_barrier" ::: "memory");
    __builtin_amdgcn_sched_barrier(0);
}

// One CKY level. LG = log2(threads-per-cell) for this level (compile-time),
// LG2 = same for next level (-1: no prefetch). MJ/MJ2 = max j-iterations.
// rcur holds this level's scores (prefetched last level); rnxt receives
// next level's scores directly from global (no LDS staging, no division).
template<int LG, int LG2, int MJ, int MJ2>
__device__ __forceinline__ void lstep(const int level, int& soff,
        const float* __restrict__ g, float2* __restrict__ chart,
        float (&rcur)[MAXJ], float (&rnxt)[MAXJ], const int tid)
{
    const int N = level;
    const int L = LEN - level;
    constexpr int TPP = 1 << LG;
    const int pos = tid >> LG;
    const int sub = tid & (TPP - 1);
    const int soff_n = soff + L * N;

    // ---- issue next level's score loads into registers (consumed next call) ----
    if constexpr (LG2 >= 0) {
        const int N2 = level + 1;
        const int L2 = L - 1;
        constexpr int TPP2 = 1 << LG2;
        const int pos2 = tid >> LG2;
        const int sub2 = tid & (TPP2 - 1);
        if (pos2 < L2) {
            const float* __restrict__ gp = g + soff_n + pos2 * N2 + sub2;
            #pragma unroll
            for (int j = 0; j < MJ2; j++) {
                const int n2 = sub2 + j * TPP2;
                if (n2 < N2) rnxt[j] = gp[j * TPP2];   // imm-offset loads
            }
        }
    }

    // ---- compute this level from chart (LDS) + rcur (registers) ----
    float bp = -INFINITY, bc = -INFINITY;
    if (pos < L) {
        #pragma unroll
        for (int j = 0; j < MJ; j++) {
            const int n = sub + j * TPP;
            if (n < N) {
                const float2 lv = chart[OFFi(n) + pos];
                const float2 rv = chart[OFFi(level - 1 - n) + pos + n + 1];
                const float x = rcur[j];
                bp = fmaxf(bp, lv.x + rv.x + x);
                bc = fmaxf(bc, lv.y + rv.y + x);
            }
        }
    }
    // reduce across the TPP lanes of each cell (aligned groups, within wave)
    #pragma unroll
    for (int mm = TPP >> 1; mm > 0; mm >>= 1) {
        bp = fmaxf(bp, __shfl_xor(bp, mm));
        bc = fmaxf(bc, __shfl_xor(bc, mm));
    }
    if (pos < L && sub == 0) {
        const int q = OFFi(level) + pos;
        float2 c = chart[q];
        c.x += bp;
        c.y += bc;
        chart[q] = c;
    }
    level_barrier();
    soff = soff_n;
}

__global__ __launch_bounds__(NT)
void cky_fused_kernel(const float* __restrict__ scores,
                      const int* __restrict__ cpos,
                      float* __restrict__ ws)
{
    __shared__ float2 chart[NCELLS];   // .x = pred chart, .y = constr chart

    const int b   = blockIdx.x;
    const int tid = threadIdx.x;
    const float* __restrict__ g = scores + (size_t)b * TOTAL;

    float rA[MAXJ], rB[MAXJ];

    // ---- prefetch level 1 scores (N=1, L=127; LG=2 mapping) ----
    {
        const int pos = tid >> 2;
        const int sub = tid & 3;
        if (pos < 127 && sub == 0) rA[0] = g[pos];
    }
    int cp = -1;
    if (tid < NCONSTR) cp = cpos[b * NCONSTR + tid];

    // ---- init both charts ----
    #pragma unroll
    for (int i = tid; i < NCELLS; i += NT) chart[i] = make_float2(0.f, 0.f);
    level_barrier();
    if (tid < NCONSTR) chart[cp].y = BONUS;   // set (not add); duplicates benign
    level_barrier();

    int soff = 0;

    // Segments by compile-time TPP (threads per cell): ceil-pow2 regimes.
    // parity: odd level consumes rA, even consumes rB.
    #pragma unroll 1
    for (int l = 1; l <= 61; l += 2) {                 // levels 1..62 (L=127..66)
        lstep<2,2,16,16>(l,     soff, g, chart, rA, rB, tid);
        lstep<2,2,16,16>(l + 1, soff, g, chart, rB, rA, tid);
    }
    lstep<2,3,16,12>(63, soff, g, chart, rA, rB, tid); // L=65 -> next L=64
    #pragma unroll 1
    for (int l = 64; l <= 92; l += 2) {                // levels 64..93 (L=64..35)
        lstep<3,3,12,12>(l,     soff, g, chart, rB, rA, tid);
        lstep<3,3,12,12>(l + 1, soff, g, chart, rA, rB, tid);
    }
    lstep<3,3,12,12>(94, soff, g, chart, rB, rA, tid);
    lstep<3,4,12,7>(95,  soff, g, chart, rA, rB, tid); // L=33 -> next L=32
    #pragma unroll 1
    for (int l = 96; l <= 108; l += 2) {               // levels 96..109 (L=32..19)
        lstep<4,4,7,7>(l,     soff, g, chart, rB, rA, tid);
        lstep<4,4,7,7>(l + 1, soff, g, chart, rA, rB, tid);
    }
    lstep<4,4,7,7>(110, soff, g, chart, rB, rA, tid);
    lstep<4,5,7,4>(111, soff, g, chart, rA, rB, tid);  // L=17 -> next L=16
    #pragma unroll 1
    for (int l = 112; l <= 116; l += 2) {              // levels 112..117 (L=16..11)
        lstep<5,5,4,4>(l,     soff, g, chart, rB, rA, tid);
        lstep<5,5,4,4>(l + 1, soff, g, chart, rA, rB, tid);
    }
    lstep<5,5,4,4>(118, soff, g, chart, rB, rA, tid);
    lstep<5,6,4,2>(119, soff, g, chart, rA, rB, tid);  // L=9 -> next L=8
    #pragma unroll 1
    for (int l = 120; l <= 124; l += 2) {              // levels 120..125 (L=8..3)
        lstep<6,6,2,2>(l,     soff, g, chart, rB, rA, tid);
        lstep<6,6,2,2>(l + 1, soff, g, chart, rA, rB, tid);
    }
    lstep<6,6,2,2>(126, soff, g, chart, rB, rA, tid);
    lstep<6,-1,2,2>(127, soff, g, chart, rA, rB, tid); // root; no prefetch

    // ---- per-batch hinge contribution ----
    if (tid == 0) {
        const float2 f = chart[NCELLS - 1];
        const float pred   = f.x;
        const float constr = f.y - BONUS * NCONSTR;
        const float diff   = pred - constr;
        const float mask   = (fabsf(diff) >= 0.001f) ? 1.f : 0.f;
        const float hinge  = fmaxf(1.0f + diff, 0.f) * mask;
        atomicAdd(ws + 0, hinge);
        atomicAdd(ws + 1, mask);
    }
}

__global__ void final_kernel(const float* __restrict__ ws, float* __restrict__ out) {
    const float h = ws[0];
    const float m = ws[1];
    out[0] = (m > 0.1f) ? (h / fmaxf(m, 1.f)) : h;
}

extern "C" void kernel_launch(void* const* d_in, const int* in_sizes, int n_in,
                              void* d_out, int out_size, void* d_ws, size_t ws_size,
                              hipStream_t stream) {
    const float* scores = (const float*)d_in[0];
    const int*   cpos   = (const int*)d_in[1];
    float* out = (float*)d_out;
    float* ws  = (float*)d_ws;

    hipMemsetAsync(ws, 0, 2 * sizeof(float), stream);
    cky_fused_kernel<<<dim3(256), dim3(NT), 0, stream>>>(scores, cpos, ws);
    final_kernel<<<dim3(1), dim3(1), 0, stream>>>(ws, out);
}